// Round 3
// baseline (184.743 us; speedup 1.0000x reference)
//
#include <hip/hip_runtime.h>
#include <math.h>

#define NB 4
#define NN 512
#define DIN 128
#define DOUT 64

typedef __attribute__((ext_vector_type(8))) short short8;
typedef __attribute__((ext_vector_type(4))) float f32x4;

__device__ __forceinline__ float fast_tanh(float x) {
    float e2 = __expf(2.0f * x);
    return 1.0f - 2.0f / (e2 + 1.0f);
}

__device__ __forceinline__ unsigned short f2bf(float f) {
    union { float f; unsigned u; } v; v.f = f;
    unsigned r = v.u + 0x7fffu + ((v.u >> 16) & 1u);  // round-nearest-even
    return (unsigned short)(r >> 16);
}

// Convert x (B*N*DIN f32) to bf16 in workspace. 65536 threads x 4 elems.
__global__ void x_to_bf16(const float* __restrict__ x, unsigned short* __restrict__ xbf) {
    const int idx = blockIdx.x * 256 + threadIdx.x;   // 0..65535
    float4 v = ((const float4*)x)[idx];
    ushort4 o;
    o.x = f2bf(v.x); o.y = f2bf(v.y); o.z = f2bf(v.z); o.w = f2bf(v.w);
    ((ushort4*)xbf)[idx] = o;
}

__global__ __launch_bounds__(256, 2) void gat_main(
    const float* __restrict__ x,            // [B][N][128] f32
    const unsigned short* __restrict__ xbf, // [B][N][128] bf16
    const float* __restrict__ apw,   // [64][128] att_proj_w
    const float* __restrict__ apb,   // [64]
    const float* __restrict__ attw,  // [64] att_weight[:,0]
    const float* __restrict__ pww,   // [64][128]
    const float* __restrict__ pwb,   // [64]
    const float* __restrict__ pow_,  // [64][128]
    const float* __restrict__ pob,   // [64]
    float* __restrict__ out)         // [B*N][64] pre-BN h
{
    __shared__ float xi[DIN];
    __shared__ float aw_s[DOUT];
    __shared__ float ab_s[DOUT];
    __shared__ float scp[4][NN];     // per-wave partial scores (8 KB)
    __shared__ float red[256];
    __shared__ float agg[DIN];
    __shared__ float bc[2];

    const int t = threadIdx.x;
    const int blk = blockIdx.x;
    const int b = blk >> 9;
    const int i = blk & 511;
    const float* xb = x + (size_t)b * NN * DIN;
    const unsigned short* xbb = xbf + (size_t)b * NN * DIN;
    const float* xrow = xb + (size_t)i * DIN;

    if (t < 32) ((float4*)xi)[t] = ((const float4*)xrow)[t];
    if (t < 64) { aw_s[t] = attw[t]; ab_s[t] = apb[t]; }
    __syncthreads();

    const int lane = t & 63, wid = t >> 6;
    const int lr = lane & 15;     // row-within-16 (A: o-local, B: j-local)
    const int g  = lane >> 4;     // k-group
    const int g8 = g * 8;

    // This wave owns o in [wid*16, wid*16+16). A[o][k] = apw[o][k] * xi[k], bf16.
    // Fragment: row lr, k = ks*32 + g8 + [0..8)
    short8 afr[4];
    {
        const float* wrow = apw + (size_t)(wid * 16 + lr) * DIN;
        #pragma unroll
        for (int ks = 0; ks < 4; ++ks) {
            float4 w0 = *(const float4*)(wrow + ks * 32 + g8);
            float4 w1 = *(const float4*)(wrow + ks * 32 + g8 + 4);
            const float* xk = xi + ks * 32 + g8;
            short8 fr;
            fr[0] = (short)f2bf(w0.x * xk[0]);
            fr[1] = (short)f2bf(w0.y * xk[1]);
            fr[2] = (short)f2bf(w0.z * xk[2]);
            fr[3] = (short)f2bf(w0.w * xk[3]);
            fr[4] = (short)f2bf(w1.x * xk[4]);
            fr[5] = (short)f2bf(w1.y * xk[5]);
            fr[6] = (short)f2bf(w1.z * xk[6]);
            fr[7] = (short)f2bf(w1.w * xk[7]);
            afr[ks] = fr;
        }
    }

    // Precompute per-lane attw/bias for the 4 o's this lane reduces (o = wid*16 + g*4 + r)
    float awr[4], abr[4];
    #pragma unroll
    for (int r = 0; r < 4; ++r) {
        const int o = wid * 16 + g * 4 + r;
        awr[r] = aw_s[o];
        abr[r] = ab_s[o];
    }

    // All 4 waves walk all 32 j-tiles (B loads redundant across waves; L1-resident)
    #pragma unroll 2
    for (int jt = 0; jt < 32; ++jt) {
        const int j0 = jt * 16;
        const short8* xr = (const short8*)(xbb + (size_t)(j0 + lr) * DIN);
        short8 bfr[4];
        #pragma unroll
        for (int ks = 0; ks < 4; ++ks) bfr[ks] = xr[ks * 4 + g];

        f32x4 acc = {0.f, 0.f, 0.f, 0.f};
        #pragma unroll
        for (int ks = 0; ks < 4; ++ks)
            acc = __builtin_amdgcn_mfma_f32_16x16x32_bf16(afr[ks], bfr[ks], acc, 0, 0, 0);

        // D: col(j-local) = lane&15, row(o-local) = g*4 + r
        float sp = 0.0f;
        #pragma unroll
        for (int r = 0; r < 4; ++r)
            sp = fmaf(awr[r], fast_tanh(acc[r] + abr[r]), sp);

        // reduce over the 4 k-groups (lanes differing in bits 4,5)
        sp += __shfl_xor(sp, 16);
        sp += __shfl_xor(sp, 32);
        if (lane < 16) scp[wid][j0 + lane] = sp;
    }
    __syncthreads();

    // sum the 4 per-wave partials, then softmax over 512
    float s0 = scp[0][t] + scp[1][t] + scp[2][t] + scp[3][t];
    float s1 = scp[0][t + 256] + scp[1][t + 256] + scp[2][t + 256] + scp[3][t + 256];
    float mx = fmaxf(s0, s1);
    #pragma unroll
    for (int msk = 1; msk < 64; msk <<= 1) mx = fmaxf(mx, __shfl_xor(mx, msk));
    if (lane == 0) red[wid] = mx;
    __syncthreads();
    if (t == 0) bc[0] = fmaxf(fmaxf(red[0], red[1]), fmaxf(red[2], red[3]));
    __syncthreads();
    const float smax = bc[0];
    float* sc = scp[0];
    float e0 = __expf(s0 - smax), e1 = __expf(s1 - smax);
    sc[t] = e0; sc[t + 256] = e1;
    float sm = e0 + e1;
    #pragma unroll
    for (int msk = 1; msk < 64; msk <<= 1) sm += __shfl_xor(sm, msk);
    __syncthreads();
    if (lane == 0) red[wid] = sm;
    __syncthreads();
    if (t == 0) bc[1] = 1.0f / (red[0] + red[1] + red[2] + red[3]);
    __syncthreads();
    const float invs = bc[1];

    // agg[d] = invs * sum_j e_j * x[b,j,d]   (f32 x for accuracy)
    {
        int d = t & 127, half = t >> 7;
        const float* xcol = xb + d;
        float a0 = 0.f, a1 = 0.f, a2 = 0.f, a3 = 0.f;
        int jb = half * 256;
        #pragma unroll 2
        for (int jj = 0; jj < 256; jj += 4) {
            int j = jb + jj;
            a0 += sc[j]     * xcol[(size_t)(j)     * DIN];
            a1 += sc[j + 1] * xcol[(size_t)(j + 1) * DIN];
            a2 += sc[j + 2] * xcol[(size_t)(j + 2) * DIN];
            a3 += sc[j + 3] * xcol[(size_t)(j + 3) * DIN];
        }
        red[t] = (a0 + a1) + (a2 + a3);
    }
    __syncthreads();
    if (t < 128) agg[t] = (red[t] + red[t + 128]) * invs;
    __syncthreads();

    // h[o] = pww[o].agg + pwb[o] + pow[o].xi + pob[o]
    {
        int o = t & 63, part = t >> 6;
        const float* wr1 = pww + (size_t)o * DIN + part * 32;
        const float* wr2 = pow_ + (size_t)o * DIN + part * 32;
        const float* ag = agg + part * 32;
        const float* xr = xi + part * 32;
        float sum = 0.0f;
        #pragma unroll
        for (int dd = 0; dd < 32; ++dd)
            sum += wr1[dd] * ag[dd] + wr2[dd] * xr[dd];
        red[t] = sum;
    }
    __syncthreads();
    if (t < 64) {
        float h = red[t] + red[t + 64] + red[t + 128] + red[t + 192] + pwb[t] + pob[t];
        out[(size_t)blk * DOUT + t] = h;
    }
}

// Per-channel batch stats over (B*N, 64); deterministic tree reduction.
__global__ void bn_stats(const float* __restrict__ h, float* __restrict__ stats) {
    const int c = blockIdx.x;
    const int t = threadIdx.x;
    float s = 0.f, s2 = 0.f;
    for (int r = t; r < NB * NN; r += 256) {
        float v = h[(size_t)r * DOUT + c];
        s += v; s2 += v * v;
    }
    __shared__ float rs[256], rs2[256];
    rs[t] = s; rs2[t] = s2;
    __syncthreads();
    for (int k = 128; k > 0; k >>= 1) {
        if (t < k) { rs[t] += rs[t + k]; rs2[t] += rs2[t + k]; }
        __syncthreads();
    }
    if (t == 0) {
        const float inv_n = 1.0f / (float)(NB * NN);
        float mean = rs[0] * inv_n;
        float var = rs2[0] * inv_n - mean * mean;   // biased, as torch BN
        stats[c] = mean;
        stats[DOUT + c] = rsqrtf(var + 1e-5f);
    }
}

__global__ void bn_selu(float* __restrict__ out, const float* __restrict__ stats,
                        const float* __restrict__ gamma, const float* __restrict__ beta) {
    const int idx = blockIdx.x * 256 + threadIdx.x;
    const int c = idx & 63;
    float v = out[idx];
    float y = (v - stats[c]) * stats[DOUT + c] * gamma[c] + beta[c];
    const float scale = 1.0507009873554805f;
    const float alpha = 1.6732632423543772f;
    out[idx] = y > 0.0f ? scale * y : scale * alpha * (__expf(y) - 1.0f);
}

extern "C" void kernel_launch(void* const* d_in, const int* in_sizes, int n_in,
                              void* d_out, int out_size, void* d_ws, size_t ws_size,
                              hipStream_t stream) {
    const float* x    = (const float*)d_in[0];
    const float* apw  = (const float*)d_in[1];
    const float* apb  = (const float*)d_in[2];
    const float* attw = (const float*)d_in[3];
    const float* pww  = (const float*)d_in[4];
    const float* pwb  = (const float*)d_in[5];
    const float* pow_ = (const float*)d_in[6];
    const float* pob  = (const float*)d_in[7];
    const float* gmm  = (const float*)d_in[8];
    const float* bta  = (const float*)d_in[9];
    float* out = (float*)d_out;
    float* stats = (float*)d_ws;                                // 128 floats
    unsigned short* xbf = (unsigned short*)((char*)d_ws + 1024); // 512 KB bf16 x

    x_to_bf16<<<256, 256, 0, stream>>>(x, xbf);
    gat_main<<<NB * NN, 256, 0, stream>>>(x, xbf, apw, apb, attw, pww, pwb, pow_, pob, out);
    bn_stats<<<DOUT, 256, 0, stream>>>(out, stats);
    bn_selu<<<(NB * NN * DOUT) / 256, 256, 0, stream>>>(out, stats, gmm, bta);
}

// Round 4
// 124.520 us; speedup vs baseline: 1.4836x; 1.4836x over previous
//
#include <hip/hip_runtime.h>
#include <math.h>

#define NB 4
#define NN 512
#define DIN 128
#define DOUT 64
#define TI 4

typedef __attribute__((ext_vector_type(8))) short short8;
typedef __attribute__((ext_vector_type(4))) float f32x4;

__device__ __forceinline__ float fast_tanh(float x) {
    float e2 = __expf(2.0f * x);
    return 1.0f - 2.0f / (e2 + 1.0f);
}

__device__ __forceinline__ unsigned short f2bf(float f) {
    union { float f; unsigned u; } v; v.f = f;
    unsigned r = v.u + 0x7fffu + ((v.u >> 16) & 1u);  // round-nearest-even
    return (unsigned short)(r >> 16);
}

__device__ __forceinline__ float bf2f(unsigned short u) {
    union { unsigned u; float f; } v; v.u = ((unsigned)u) << 16; return v.f;
}

// Convert x (B*N*DIN f32) to bf16 in workspace. 256 blocks x 256 threads x 4 elems.
__global__ void x_to_bf16(const float* __restrict__ x, unsigned short* __restrict__ xbf) {
    const int idx = blockIdx.x * 256 + threadIdx.x;   // 0..65535
    float4 v = ((const float4*)x)[idx];
    ushort4 o;
    o.x = f2bf(v.x); o.y = f2bf(v.y); o.z = f2bf(v.z); o.w = f2bf(v.w);
    ((ushort4*)xbf)[idx] = o;
}

__global__ __launch_bounds__(512, 2) void gat_main(
    const float* __restrict__ x,            // [B][N][128] f32
    const unsigned short* __restrict__ xbf, // [B][N][128] bf16
    const float* __restrict__ apw,   // [64][128]
    const float* __restrict__ apb,   // [64]
    const float* __restrict__ attw,  // [64]
    const float* __restrict__ pww,   // [64][128]
    const float* __restrict__ pwb,   // [64]
    const float* __restrict__ pow_,  // [64][128]
    const float* __restrict__ pob,   // [64]
    float* __restrict__ out)         // [B*N][64] pre-BN h
{
    __shared__ float xis[TI][DIN];          // 2 KB: the 4 query rows, f32
    __shared__ float aw_s[DOUT];
    __shared__ float ab_s[DOUT];
    __shared__ float scp[4][TI][NN];        // 32 KB: per-o-group partial scores
    __shared__ float red_m[8][TI];
    __shared__ float red_s[8][TI];
    __shared__ float bcm[TI];
    __shared__ float bcs[TI];
    __shared__ float pagg[4][TI][DIN];      // 8 KB
    __shared__ float aggs[TI][DIN];         // 2 KB
    __shared__ float pr[8][DOUT];           // 2 KB

    const int t = threadIdx.x;
    const int blk = blockIdx.x;             // 0..511
    const int b = blk >> 7;                 // 128 blocks per batch
    const int rowbase = (blk & 127) * TI;   // local query-row base
    const float* xb = x + (size_t)b * NN * DIN;
    const unsigned short* xbb = xbf + (size_t)b * NN * DIN;

    // stage the 4 query rows (f32) + attention params
    {
        int i = t >> 7, d = t & 127;
        xis[i][d] = xb[(size_t)(rowbase + i) * DIN + d];
    }
    if (t < 64) { aw_s[t] = attw[t]; ab_s[t] = apb[t]; }
    __syncthreads();

    const int lane = t & 63, wid = t >> 6;
    const int og = wid & 3;        // o-group: o in [og*16, og*16+16)
    const int jh = wid >> 2;       // j-half: j in [jh*256, jh*256+256)
    const int lr = lane & 15;
    const int g = lane >> 4;
    const int g8 = g * 8;

    // A-fragments for 4 i's: afr[i][ks], row o = og*16+lr, k = ks*32+g8+[0..8)
    short8 afr[TI][4];
    {
        const float* wrow = apw + (size_t)(og * 16 + lr) * DIN;
        #pragma unroll
        for (int ks = 0; ks < 4; ++ks) {
            float4 w0 = *(const float4*)(wrow + ks * 32 + g8);
            float4 w1 = *(const float4*)(wrow + ks * 32 + g8 + 4);
            #pragma unroll
            for (int i = 0; i < TI; ++i) {
                const float* xk = &xis[i][ks * 32 + g8];
                short8 fr;
                fr[0] = (short)f2bf(w0.x * xk[0]);
                fr[1] = (short)f2bf(w0.y * xk[1]);
                fr[2] = (short)f2bf(w0.z * xk[2]);
                fr[3] = (short)f2bf(w0.w * xk[3]);
                fr[4] = (short)f2bf(w1.x * xk[4]);
                fr[5] = (short)f2bf(w1.y * xk[5]);
                fr[6] = (short)f2bf(w1.z * xk[6]);
                fr[7] = (short)f2bf(w1.w * xk[7]);
                afr[i][ks] = fr;
            }
        }
    }

    float awr[4], abr[4];   // the 4 o's this lane reduces: o = og*16 + g*4 + r
    #pragma unroll
    for (int r = 0; r < 4; ++r) {
        const int o = og * 16 + g * 4 + r;
        awr[r] = aw_s[o];
        abr[r] = ab_s[o];
    }

    // score loop: this wave covers 16 j-tiles of its half, all 4 i's
    #pragma unroll 2
    for (int jt = 0; jt < 16; ++jt) {
        const int j0 = jh * 256 + jt * 16;
        const short8* xr = (const short8*)(xbb + (size_t)(j0 + lr) * DIN);
        short8 bfr[4];
        #pragma unroll
        for (int ks = 0; ks < 4; ++ks) bfr[ks] = xr[ks * 4 + g];

        #pragma unroll
        for (int i = 0; i < TI; ++i) {
            f32x4 acc = {0.f, 0.f, 0.f, 0.f};
            #pragma unroll
            for (int ks = 0; ks < 4; ++ks)
                acc = __builtin_amdgcn_mfma_f32_16x16x32_bf16(afr[i][ks], bfr[ks], acc, 0, 0, 0);
            float sp = 0.0f;
            #pragma unroll
            for (int r = 0; r < 4; ++r)
                sp = fmaf(awr[r], fast_tanh(acc[r] + abr[r]), sp);
            sp += __shfl_xor(sp, 16);
            sp += __shfl_xor(sp, 32);
            if (lane < 16) scp[og][i][j0 + lane] = sp;
        }
    }
    __syncthreads();

    // softmax: thread t owns column j=t for all 4 i's
    float s[TI], e[TI];
    #pragma unroll
    for (int i = 0; i < TI; ++i)
        s[i] = scp[0][i][t] + scp[1][i][t] + scp[2][i][t] + scp[3][i][t];
    {
        float m[TI];
        #pragma unroll
        for (int i = 0; i < TI; ++i) m[i] = s[i];
        #pragma unroll
        for (int msk = 1; msk < 64; msk <<= 1)
            #pragma unroll
            for (int i = 0; i < TI; ++i) m[i] = fmaxf(m[i], __shfl_xor(m[i], msk));
        if (lane == 0)
            #pragma unroll
            for (int i = 0; i < TI; ++i) red_m[wid][i] = m[i];
    }
    __syncthreads();
    if (t < TI) {
        float mm = red_m[0][t];
        #pragma unroll
        for (int w = 1; w < 8; ++w) mm = fmaxf(mm, red_m[w][t]);
        bcm[t] = mm;
    }
    __syncthreads();
    float* esc = &scp[0][0][0];   // reuse scp[0] as e[TI][NN]
    {
        float ss[TI];
        #pragma unroll
        for (int i = 0; i < TI; ++i) {
            e[i] = __expf(s[i] - bcm[i]);
            esc[i * NN + t] = e[i];
            ss[i] = e[i];
        }
        #pragma unroll
        for (int msk = 1; msk < 64; msk <<= 1)
            #pragma unroll
            for (int i = 0; i < TI; ++i) ss[i] += __shfl_xor(ss[i], msk);
        if (lane == 0)
            #pragma unroll
            for (int i = 0; i < TI; ++i) red_s[wid][i] = ss[i];
    }
    __syncthreads();
    if (t < TI) {
        float sm = 0.f;
        #pragma unroll
        for (int w = 0; w < 8; ++w) sm += red_s[w][t];
        bcs[t] = 1.0f / sm;
    }
    __syncthreads();

    // agg: thread (d = t&127, q = t>>7) does j-quarter, x read once for 4 i's
    {
        const int d = t & 127, q = t >> 7;
        float a[TI] = {0.f, 0.f, 0.f, 0.f};
        const unsigned short* xc = xbb + d;
        for (int jj = q * 128; jj < q * 128 + 128; ++jj) {
            float xv = bf2f(xc[(size_t)jj * DIN]);
            #pragma unroll
            for (int i = 0; i < TI; ++i) a[i] = fmaf(esc[i * NN + jj], xv, a[i]);
        }
        #pragma unroll
        for (int i = 0; i < TI; ++i) pagg[q][i][d] = a[i];
    }
    __syncthreads();
    {
        const int i = t >> 7, d = t & 127;
        aggs[i][d] = (pagg[0][i][d] + pagg[1][i][d] + pagg[2][i][d] + pagg[3][i][d]) * bcs[i];
    }
    __syncthreads();

    // projections: thread (o = t&63, pi = t>>6): i = pi>>1, d-half = pi&1
    {
        const int o = t & 63, pi = t >> 6;
        const int i = pi >> 1, part = pi & 1;
        const float* w1 = pww + (size_t)o * DIN + part * 64;
        const float* w2 = pow_ + (size_t)o * DIN + part * 64;
        const float* ag = &aggs[i][part * 64];
        const float* xr = &xis[i][part * 64];
        float sum = 0.0f;
        #pragma unroll
        for (int dd = 0; dd < 64; ++dd)
            sum += w1[dd] * ag[dd] + w2[dd] * xr[dd];
        pr[pi][o] = sum;
    }
    __syncthreads();
    if (t < TI * DOUT) {
        const int i = t >> 6, o = t & 63;
        float h = pr[i * 2][o] + pr[i * 2 + 1][o] + pwb[o] + pob[o];
        out[((size_t)blk * TI + i) * DOUT + o] = h;
    }
}

// Per-channel batch stats over (B*N, 64); deterministic tree reduction.
__global__ void bn_stats(const float* __restrict__ h, float* __restrict__ stats) {
    const int c = blockIdx.x;
    const int t = threadIdx.x;
    float s = 0.f, s2 = 0.f;
    for (int r = t; r < NB * NN; r += 256) {
        float v = h[(size_t)r * DOUT + c];
        s += v; s2 += v * v;
    }
    __shared__ float rs[256], rs2[256];
    rs[t] = s; rs2[t] = s2;
    __syncthreads();
    for (int k = 128; k > 0; k >>= 1) {
        if (t < k) { rs[t] += rs[t + k]; rs2[t] += rs2[t + k]; }
        __syncthreads();
    }
    if (t == 0) {
        const float inv_n = 1.0f / (float)(NB * NN);
        float mean = rs[0] * inv_n;
        float var = rs2[0] * inv_n - mean * mean;   // biased, as torch BN
        stats[c] = mean;
        stats[DOUT + c] = rsqrtf(var + 1e-5f);
    }
}

__global__ void bn_selu(float* __restrict__ out, const float* __restrict__ stats,
                        const float* __restrict__ gamma, const float* __restrict__ beta) {
    const int idx = blockIdx.x * 256 + threadIdx.x;
    const int c = idx & 63;
    float v = out[idx];
    float y = (v - stats[c]) * stats[DOUT + c] * gamma[c] + beta[c];
    const float scale = 1.0507009873554805f;
    const float alpha = 1.6732632423543772f;
    out[idx] = y > 0.0f ? scale * y : scale * alpha * (__expf(y) - 1.0f);
}

extern "C" void kernel_launch(void* const* d_in, const int* in_sizes, int n_in,
                              void* d_out, int out_size, void* d_ws, size_t ws_size,
                              hipStream_t stream) {
    const float* x    = (const float*)d_in[0];
    const float* apw  = (const float*)d_in[1];
    const float* apb  = (const float*)d_in[2];
    const float* attw = (const float*)d_in[3];
    const float* pww  = (const float*)d_in[4];
    const float* pwb  = (const float*)d_in[5];
    const float* pow_ = (const float*)d_in[6];
    const float* pob  = (const float*)d_in[7];
    const float* gmm  = (const float*)d_in[8];
    const float* bta  = (const float*)d_in[9];
    float* out = (float*)d_out;
    float* stats = (float*)d_ws;                                 // 128 floats
    unsigned short* xbf = (unsigned short*)((char*)d_ws + 1024); // 512 KB bf16 x

    x_to_bf16<<<256, 256, 0, stream>>>(x, xbf);
    gat_main<<<NB * NN / TI, 512, 0, stream>>>(x, xbf, apw, apb, attw, pww, pwb, pow_, pob, out);
    bn_stats<<<DOUT, 256, 0, stream>>>(out, stats);
    bn_selu<<<(NB * NN * DOUT) / 256, 256, 0, stream>>>(out, stats, gmm, bta);
}

// Round 5
// 107.128 us; speedup vs baseline: 1.7245x; 1.1624x over previous
//
#include <hip/hip_runtime.h>
#include <math.h>

#define NB 4
#define NN 512
#define DIN 128
#define DOUT 64
#define TI 2
#define CHROWS 64
#define NCH (NN / CHROWS)

typedef __attribute__((ext_vector_type(8))) short short8;
typedef __attribute__((ext_vector_type(8))) unsigned short ushort8;
typedef __attribute__((ext_vector_type(4))) float f32x4;

__device__ __forceinline__ unsigned short f2bf(float f) {
    union { float f; unsigned u; } v; v.f = f;
    unsigned r = v.u + 0x7fffu + ((v.u >> 16) & 1u);  // round-nearest-even
    return (unsigned short)(r >> 16);
}

__device__ __forceinline__ float bf2f(unsigned short u) {
    union { unsigned u; float f; } v; v.u = ((unsigned)u) << 16; return v.f;
}

// Convert x (B*N*DIN f32) to bf16 in workspace.
__global__ void x_to_bf16(const float* __restrict__ x, unsigned short* __restrict__ xbf) {
    const int idx = blockIdx.x * 256 + threadIdx.x;   // 0..65535
    float4 v = ((const float4*)x)[idx];
    ushort4 o;
    o.x = f2bf(v.x); o.y = f2bf(v.y); o.z = f2bf(v.z); o.w = f2bf(v.w);
    ((ushort4*)xbf)[idx] = o;
}

__global__ __launch_bounds__(512, 6) void gat_main(
    const float* __restrict__ x,            // [B][N][128] f32
    const unsigned short* __restrict__ xbf, // [B][N][128] bf16
    const float* __restrict__ apw,   // [64][128]
    const float* __restrict__ apb,   // [64]
    const float* __restrict__ attw,  // [64]
    const float* __restrict__ pww,   // [64][128]
    const float* __restrict__ pwb,   // [64]
    const float* __restrict__ pow_,  // [64][128]
    const float* __restrict__ pob,   // [64]
    float* __restrict__ out)         // [B*N][64] pre-BN h
{
    __shared__ unsigned short xt[CHROWS * DIN];   // 16 KB swizzled x-tile; aliased in epilogue
    __shared__ float scp[4][TI][NN];              // 16 KB partial scores / exp
    __shared__ float xis[TI][DIN];                // 1 KB query rows f32
    __shared__ float aw_s[DOUT];
    __shared__ float ab_s[DOUT];
    __shared__ float red_s[8][TI];
    __shared__ float bcs[TI];

    // epilogue scratch aliased into xt (xt dead after score loop)
    float* pagg = (float*)xt;                     // [4][TI][DIN] 4 KB
    float* aggs = pagg + 4 * TI * DIN;            // [TI][DIN] 1 KB
    float* pr   = aggs + TI * DIN;                // [8][DOUT] 2 KB

    const int t = threadIdx.x;
    const int blk = blockIdx.x;              // 0..1023
    const int b = blk >> 8;                  // 256 blocks per batch
    const int rowbase = (blk & 255) * TI;
    const float* xb = x + (size_t)b * NN * DIN;
    const unsigned short* xbb = xbf + (size_t)b * NN * DIN;

    if (t < TI * DIN) {
        int i = t >> 7, d = t & 127;
        xis[i][d] = xb[(size_t)(rowbase + i) * DIN + d];
    }
    if (t < 64) { aw_s[t] = attw[t]; ab_s[t] = apb[t]; }
    __syncthreads();

    const int lane = t & 63, wid = t >> 6;
    const int og = wid & 3;          // o in [og*16, og*16+16)
    const int jsub = wid >> 2;       // rows [jsub*32, jsub*32+32) of each chunk
    const int lr = lane & 15;
    const int g = lane >> 4;
    const int g8 = g * 8;

    // A-fragments: afr[i][ks], row o = og*16+lr, k = ks*32+g8+[0..8)
    short8 afr[TI][4];
    {
        const float* wrow = apw + (size_t)(og * 16 + lr) * DIN;
        #pragma unroll
        for (int ks = 0; ks < 4; ++ks) {
            float4 w0 = *(const float4*)(wrow + ks * 32 + g8);
            float4 w1 = *(const float4*)(wrow + ks * 32 + g8 + 4);
            #pragma unroll
            for (int i = 0; i < TI; ++i) {
                const float* xk = &xis[i][ks * 32 + g8];
                short8 fr;
                fr[0] = (short)f2bf(w0.x * xk[0]);
                fr[1] = (short)f2bf(w0.y * xk[1]);
                fr[2] = (short)f2bf(w0.z * xk[2]);
                fr[3] = (short)f2bf(w0.w * xk[3]);
                fr[4] = (short)f2bf(w1.x * xk[4]);
                fr[5] = (short)f2bf(w1.y * xk[5]);
                fr[6] = (short)f2bf(w1.z * xk[6]);
                fr[7] = (short)f2bf(w1.w * xk[7]);
                afr[i][ks] = fr;
            }
        }
    }

    // per-lane tanh constants for its 4 o's: o = og*16 + g*4 + r
    // w*tanh(T) = w - 2w * rcp(exp2(T*C2) + 1),  C2 = 2*log2(e)
    const float C2 = 2.885390081777927f;
    float awm2[4], abc[4], sumw = 0.0f;
    #pragma unroll
    for (int r = 0; r < 4; ++r) {
        const int o = og * 16 + g * 4 + r;
        float w = aw_s[o];
        awm2[r] = -2.0f * w;
        abc[r] = ab_s[o] * C2;
        sumw += w;
    }

    // score loop: 8 chunks of 64 j-rows staged in LDS (granule-XOR swizzle)
    for (int ch = 0; ch < NCH; ++ch) {
        const ushort8* src = (const ushort8*)(xbb + (size_t)ch * CHROWS * DIN);
        ushort8 v0 = src[t * 2];
        ushort8 v1 = src[t * 2 + 1];
        __syncthreads();   // previous chunk's reads done
        {
            const int row = t >> 3;
            const int k = row & 7;
            const int gr0 = (t * 2) & 15, gr1 = gr0 + 1;
            *(ushort8*)((char*)xt + row * 256 + ((gr0 ^ k) * 16)) = v0;
            *(ushort8*)((char*)xt + row * 256 + ((gr1 ^ k) * 16)) = v1;
        }
        __syncthreads();   // tile visible

        #pragma unroll
        for (int jtc = 0; jtc < 2; ++jtc) {
            const int rloc = jsub * 32 + jtc * 16 + lr;   // row in tile
            const int j0 = ch * CHROWS + jsub * 32 + jtc * 16;
            short8 bfr[4];
            #pragma unroll
            for (int ks = 0; ks < 4; ++ks)
                bfr[ks] = *(const short8*)((const char*)xt + rloc * 256 +
                                           (((ks * 4 + g) ^ (rloc & 7)) * 16));
            #pragma unroll
            for (int i = 0; i < TI; ++i) {
                f32x4 acc = {0.f, 0.f, 0.f, 0.f};
                #pragma unroll
                for (int ks = 0; ks < 4; ++ks)
                    acc = __builtin_amdgcn_mfma_f32_16x16x32_bf16(afr[i][ks], bfr[ks], acc, 0, 0, 0);
                float sp = sumw;
                #pragma unroll
                for (int r = 0; r < 4; ++r) {
                    float arg = fmaf(acc[r], C2, abc[r]);
                    float u, rc;
                    asm("v_exp_f32 %0, %1" : "=v"(u) : "v"(arg));
                    float den = u + 1.0f;
                    asm("v_rcp_f32 %0, %1" : "=v"(rc) : "v"(den));
                    sp = fmaf(awm2[r], rc, sp);
                }
                sp += __shfl_xor(sp, 16);
                sp += __shfl_xor(sp, 32);
                if (lane < 16) scp[og][i][j0 + lane] = sp;
            }
        }
    }
    __syncthreads();

    // softmax over j (no max-subtraction: |score| <= sum|w| ~ 8, f32-safe)
    float s0 = scp[0][0][t] + scp[1][0][t] + scp[2][0][t] + scp[3][0][t];
    float s1 = scp[0][1][t] + scp[1][1][t] + scp[2][1][t] + scp[3][1][t];
    float e0 = __expf(s0), e1 = __expf(s1);
    scp[0][0][t] = e0;   // esc[0][j]
    scp[0][1][t] = e1;   // esc[1][j]
    float ss0 = e0, ss1 = e1;
    #pragma unroll
    for (int msk = 1; msk < 64; msk <<= 1) {
        ss0 += __shfl_xor(ss0, msk);
        ss1 += __shfl_xor(ss1, msk);
    }
    if (lane == 0) { red_s[wid][0] = ss0; red_s[wid][1] = ss1; }
    __syncthreads();
    if (t < TI) {
        float sm = 0.f;
        #pragma unroll
        for (int w = 0; w < 8; ++w) sm += red_s[w][t];
        bcs[t] = 1.0f / sm;
    }
    __syncthreads();

    // agg[i][d] = invs_i * sum_j e[i][j] * x[b,j,d]
    const float* esc0 = &scp[0][0][0];
    const float* esc1 = &scp[0][1][0];
    {
        const int d = t & 127, q = t >> 7;
        const unsigned short* xc = xbb + d;
        float a0 = 0.f, a1 = 0.f;
        for (int jj = q * 128; jj < q * 128 + 128; ++jj) {
            float xv = bf2f(xc[(size_t)jj * DIN]);
            a0 = fmaf(esc0[jj], xv, a0);
            a1 = fmaf(esc1[jj], xv, a1);
        }
        pagg[(q * TI + 0) * DIN + d] = a0;
        pagg[(q * TI + 1) * DIN + d] = a1;
    }
    __syncthreads();
    if (t < TI * DIN) {
        const int i = t >> 7, d = t & 127;
        aggs[i * DIN + d] = (pagg[(0 * TI + i) * DIN + d] + pagg[(1 * TI + i) * DIN + d] +
                             pagg[(2 * TI + i) * DIN + d] + pagg[(3 * TI + i) * DIN + d]) * bcs[i];
    }
    __syncthreads();

    // projections: pi = t>>6 in 0..7 -> i = pi>>2, d-part = pi&3 (32 d each)
    {
        const int o = t & 63, pi = t >> 6;
        const int i = pi >> 2, part = pi & 3;
        const float* w1 = pww + (size_t)o * DIN + part * 32;
        const float* w2 = pow_ + (size_t)o * DIN + part * 32;
        const float* ag = aggs + i * DIN + part * 32;
        const float* xr = &xis[i][part * 32];
        float sum = 0.0f;
        #pragma unroll
        for (int dd = 0; dd < 32; ++dd)
            sum += w1[dd] * ag[dd] + w2[dd] * xr[dd];
        pr[pi * DOUT + o] = sum;
    }
    __syncthreads();
    if (t < TI * DOUT) {
        const int i = t >> 6, o = t & 63;
        float h = pr[(i * 4 + 0) * DOUT + o] + pr[(i * 4 + 1) * DOUT + o] +
                  pr[(i * 4 + 2) * DOUT + o] + pr[(i * 4 + 3) * DOUT + o] +
                  pwb[o] + pob[o];
        out[(size_t)(b * NN + rowbase + i) * DOUT + o] = h;
    }
}

// Per-channel batch stats over (B*N, 64); deterministic tree reduction.
__global__ void bn_stats(const float* __restrict__ h, float* __restrict__ stats) {
    const int c = blockIdx.x;
    const int t = threadIdx.x;
    float s = 0.f, s2 = 0.f;
    for (int r = t; r < NB * NN; r += 256) {
        float v = h[(size_t)r * DOUT + c];
        s += v; s2 += v * v;
    }
    __shared__ float rs[256], rs2[256];
    rs[t] = s; rs2[t] = s2;
    __syncthreads();
    for (int k = 128; k > 0; k >>= 1) {
        if (t < k) { rs[t] += rs[t + k]; rs2[t] += rs2[t + k]; }
        __syncthreads();
    }
    if (t == 0) {
        const float inv_n = 1.0f / (float)(NB * NN);
        float mean = rs[0] * inv_n;
        float var = rs2[0] * inv_n - mean * mean;   // biased, as torch BN
        stats[c] = mean;
        stats[DOUT + c] = rsqrtf(var + 1e-5f);
    }
}

__global__ void bn_selu(float* __restrict__ out, const float* __restrict__ stats,
                        const float* __restrict__ gamma, const float* __restrict__ beta) {
    const int idx = blockIdx.x * 256 + threadIdx.x;
    const int c = idx & 63;
    float v = out[idx];
    float y = (v - stats[c]) * stats[DOUT + c] * gamma[c] + beta[c];
    const float scale = 1.0507009873554805f;
    const float alpha = 1.6732632423543772f;
    out[idx] = y > 0.0f ? scale * y : scale * alpha * (__expf(y) - 1.0f);
}

extern "C" void kernel_launch(void* const* d_in, const int* in_sizes, int n_in,
                              void* d_out, int out_size, void* d_ws, size_t ws_size,
                              hipStream_t stream) {
    const float* x    = (const float*)d_in[0];
    const float* apw  = (const float*)d_in[1];
    const float* apb  = (const float*)d_in[2];
    const float* attw = (const float*)d_in[3];
    const float* pww  = (const float*)d_in[4];
    const float* pwb  = (const float*)d_in[5];
    const float* pow_ = (const float*)d_in[6];
    const float* pob  = (const float*)d_in[7];
    const float* gmm  = (const float*)d_in[8];
    const float* bta  = (const float*)d_in[9];
    float* out = (float*)d_out;
    float* stats = (float*)d_ws;                                 // 128 floats
    unsigned short* xbf = (unsigned short*)((char*)d_ws + 1024); // 512 KB bf16 x

    x_to_bf16<<<256, 256, 0, stream>>>(x, xbf);
    gat_main<<<NB * NN / TI, 512, 0, stream>>>(x, xbf, apw, apb, attw, pww, pwb, pow_, pob, out);
    bn_stats<<<DOUT, 256, 0, stream>>>(out, stats);
    bn_selu<<<(NB * NN * DOUT) / 256, 256, 0, stream>>>(out, stats, gmm, bta);
}

// Round 6
// 94.547 us; speedup vs baseline: 1.9540x; 1.1331x over previous
//
#include <hip/hip_runtime.h>
#include <math.h>

#define NB 4
#define NN 512
#define DIN 128
#define DOUT 64
#define TI 2
#define CHROWS 64
#define NCH (NN / CHROWS)

typedef __attribute__((ext_vector_type(8))) short short8;
typedef __attribute__((ext_vector_type(8))) unsigned short ushort8;
typedef __attribute__((ext_vector_type(4))) float f32x4;

__device__ __forceinline__ unsigned short f2bf(float f) {
    union { float f; unsigned u; } v; v.f = f;
    unsigned r = v.u + 0x7fffu + ((v.u >> 16) & 1u);  // round-nearest-even
    return (unsigned short)(r >> 16);
}

__device__ __forceinline__ float bf2f(unsigned short u) {
    union { unsigned u; float f; } v; v.u = ((unsigned)u) << 16; return v.f;
}

// Convert x (B*N*DIN f32) to bf16 in workspace.
__global__ void x_to_bf16(const float* __restrict__ x, unsigned short* __restrict__ xbf) {
    const int idx = blockIdx.x * 256 + threadIdx.x;   // 0..65535
    float4 v = ((const float4*)x)[idx];
    ushort4 o;
    o.x = f2bf(v.x); o.y = f2bf(v.y); o.z = f2bf(v.z); o.w = f2bf(v.w);
    ((ushort4*)xbf)[idx] = o;
}

__global__ __launch_bounds__(512, 4) void gat_main(
    const float* __restrict__ x,            // [B][N][128] f32
    const unsigned short* __restrict__ xbf, // [B][N][128] bf16
    const float* __restrict__ apw,   // [64][128]
    const float* __restrict__ apb,   // [64]
    const float* __restrict__ attw,  // [64]
    const float* __restrict__ pww,   // [64][128]
    const float* __restrict__ pwb,   // [64]
    const float* __restrict__ pow_,  // [64][128]
    const float* __restrict__ pob,   // [64]
    float* __restrict__ out)         // [B*N][64] pre-BN h
{
    __shared__ unsigned short xt[CHROWS * DIN];   // 16 KB swizzled x-tile; aliased in epilogue
    __shared__ float scp[4][TI][NN];              // 16 KB partial scores / exp
    __shared__ float xis[TI][DIN];                // 1 KB query rows f32
    __shared__ float aw_s[DOUT];
    __shared__ float ab_s[DOUT];
    __shared__ float red_s[8][TI];
    __shared__ float bcs[TI];

    // epilogue scratch aliased into xt (xt dead after score loop)
    float* pagg = (float*)xt;                     // [4][TI][DIN] 4 KB
    float* aggs = pagg + 4 * TI * DIN;            // [TI][DIN] 1 KB
    float* pr   = aggs + TI * DIN;                // [8][DOUT] 2 KB

    const int t = threadIdx.x;
    const int blk = blockIdx.x;              // 0..1023
    const int b = blk >> 8;                  // 256 blocks per batch
    const int rowbase = (blk & 255) * TI;
    const float* xb = x + (size_t)b * NN * DIN;
    const unsigned short* xbb = xbf + (size_t)b * NN * DIN;

    if (t < TI * DIN) {
        int i = t >> 7, d = t & 127;
        xis[i][d] = xb[(size_t)(rowbase + i) * DIN + d];
    }
    if (t < 64) { aw_s[t] = attw[t]; ab_s[t] = apb[t]; }
    __syncthreads();

    const int lane = t & 63, wid = t >> 6;
    const int og = wid & 3;          // o in [og*16, og*16+16)
    const int jsub = wid >> 2;       // rows [jsub*32, jsub*32+32) of each chunk
    const int lr = lane & 15;
    const int g = lane >> 4;
    const int g8 = g * 8;

    // A-fragments: afr[i][ks], row o = og*16+lr, k = ks*32+g8+[0..8)
    short8 afr[TI][4];
    {
        const float* wrow = apw + (size_t)(og * 16 + lr) * DIN;
        #pragma unroll
        for (int ks = 0; ks < 4; ++ks) {
            float4 w0 = *(const float4*)(wrow + ks * 32 + g8);
            float4 w1 = *(const float4*)(wrow + ks * 32 + g8 + 4);
            #pragma unroll
            for (int i = 0; i < TI; ++i) {
                const float* xk = &xis[i][ks * 32 + g8];
                short8 fr;
                fr[0] = (short)f2bf(w0.x * xk[0]);
                fr[1] = (short)f2bf(w0.y * xk[1]);
                fr[2] = (short)f2bf(w0.z * xk[2]);
                fr[3] = (short)f2bf(w0.w * xk[3]);
                fr[4] = (short)f2bf(w1.x * xk[4]);
                fr[5] = (short)f2bf(w1.y * xk[5]);
                fr[6] = (short)f2bf(w1.z * xk[6]);
                fr[7] = (short)f2bf(w1.w * xk[7]);
                afr[i][ks] = fr;
            }
        }
    }

    // per-lane tanh constants for its 4 o's: o = og*16 + g*4 + r
    // w*tanh(T) = w - 2w * rcp(exp2(T*C2) + 1),  C2 = 2*log2(e)
    const float C2 = 2.885390081777927f;
    float awm2[4], abc[4], sumw = 0.0f;
    #pragma unroll
    for (int r = 0; r < 4; ++r) {
        const int o = og * 16 + g * 4 + r;
        float w = aw_s[o];
        awm2[r] = -2.0f * w;
        abc[r] = ab_s[o] * C2;
        sumw += w;
    }

    // score loop: 8 chunks of 64 j-rows staged in LDS (granule-XOR swizzle)
    for (int ch = 0; ch < NCH; ++ch) {
        const ushort8* src = (const ushort8*)(xbb + (size_t)ch * CHROWS * DIN);
        ushort8 v0 = src[t * 2];
        ushort8 v1 = src[t * 2 + 1];
        __syncthreads();   // previous chunk's reads done
        {
            const int row = t >> 3;
            const int k = row & 7;
            const int gr0 = (t * 2) & 15, gr1 = gr0 + 1;
            *(ushort8*)((char*)xt + row * 256 + ((gr0 ^ k) * 16)) = v0;
            *(ushort8*)((char*)xt + row * 256 + ((gr1 ^ k) * 16)) = v1;
        }
        __syncthreads();   // tile visible

        #pragma unroll
        for (int jtc = 0; jtc < 2; ++jtc) {
            const int rloc = jsub * 32 + jtc * 16 + lr;   // row in tile
            const int j0 = ch * CHROWS + jsub * 32 + jtc * 16;
            short8 bfr[4];
            #pragma unroll
            for (int ks = 0; ks < 4; ++ks)
                bfr[ks] = *(const short8*)((const char*)xt + rloc * 256 +
                                           (((ks * 4 + g) ^ (rloc & 7)) * 16));
            #pragma unroll
            for (int i = 0; i < TI; ++i) {
                f32x4 acc = {0.f, 0.f, 0.f, 0.f};
                #pragma unroll
                for (int ks = 0; ks < 4; ++ks)
                    acc = __builtin_amdgcn_mfma_f32_16x16x32_bf16(afr[i][ks], bfr[ks], acc, 0, 0, 0);
                float sp = sumw;
                #pragma unroll
                for (int r = 0; r < 4; ++r) {
                    float arg = fmaf(acc[r], C2, abc[r]);
                    float u, rc;
                    asm("v_exp_f32 %0, %1" : "=v"(u) : "v"(arg));
                    float den = u + 1.0f;
                    asm("v_rcp_f32 %0, %1" : "=v"(rc) : "v"(den));
                    sp = fmaf(awm2[r], rc, sp);
                }
                sp += __shfl_xor(sp, 16);
                sp += __shfl_xor(sp, 32);
                if (lane < 16) scp[og][i][j0 + lane] = sp;
            }
        }
    }
    __syncthreads();

    // softmax over j (no max-subtraction: |score| <= sum|w| ~ 8, f32-safe)
    float s0 = scp[0][0][t] + scp[1][0][t] + scp[2][0][t] + scp[3][0][t];
    float s1 = scp[0][1][t] + scp[1][1][t] + scp[2][1][t] + scp[3][1][t];
    float e0 = __expf(s0), e1 = __expf(s1);
    scp[0][0][t] = e0;   // esc[0][j]
    scp[0][1][t] = e1;   // esc[1][j]
    float ss0 = e0, ss1 = e1;
    #pragma unroll
    for (int msk = 1; msk < 64; msk <<= 1) {
        ss0 += __shfl_xor(ss0, msk);
        ss1 += __shfl_xor(ss1, msk);
    }
    if (lane == 0) { red_s[wid][0] = ss0; red_s[wid][1] = ss1; }
    __syncthreads();
    if (t < TI) {
        float sm = 0.f;
        #pragma unroll
        for (int w = 0; w < 8; ++w) sm += red_s[w][t];
        bcs[t] = 1.0f / sm;
    }
    __syncthreads();

    // agg[i][d] = invs_i * sum_j e[i][j] * x[b,j,d]
    const float* esc0 = &scp[0][0][0];
    const float* esc1 = &scp[0][1][0];
    {
        const int d = t & 127, q = t >> 7;
        const unsigned short* xc = xbb + d;
        float a0 = 0.f, a1 = 0.f;
        for (int jj = q * 128; jj < q * 128 + 128; ++jj) {
            float xv = bf2f(xc[(size_t)jj * DIN]);
            a0 = fmaf(esc0[jj], xv, a0);
            a1 = fmaf(esc1[jj], xv, a1);
        }
        pagg[(q * TI + 0) * DIN + d] = a0;
        pagg[(q * TI + 1) * DIN + d] = a1;
    }
    __syncthreads();
    if (t < TI * DIN) {
        const int i = t >> 7, d = t & 127;
        aggs[i * DIN + d] = (pagg[(0 * TI + i) * DIN + d] + pagg[(1 * TI + i) * DIN + d] +
                             pagg[(2 * TI + i) * DIN + d] + pagg[(3 * TI + i) * DIN + d]) * bcs[i];
    }
    __syncthreads();

    // projections: pi = t>>6 in 0..7 -> i = pi>>2, d-part = pi&3 (32 d each)
    {
        const int o = t & 63, pi = t >> 6;
        const int i = pi >> 2, part = pi & 3;
        const float* w1 = pww + (size_t)o * DIN + part * 32;
        const float* w2 = pow_ + (size_t)o * DIN + part * 32;
        const float* ag = aggs + i * DIN + part * 32;
        const float* xr = &xis[i][part * 32];
        float sum = 0.0f;
        #pragma unroll
        for (int dd = 0; dd < 32; ++dd)
            sum += w1[dd] * ag[dd] + w2[dd] * xr[dd];
        pr[pi * DOUT + o] = sum;
    }
    __syncthreads();
    if (t < TI * DOUT) {
        const int i = t >> 6, o = t & 63;
        float h = pr[(i * 4 + 0) * DOUT + o] + pr[(i * 4 + 1) * DOUT + o] +
                  pr[(i * 4 + 2) * DOUT + o] + pr[(i * 4 + 3) * DOUT + o] +
                  pwb[o] + pob[o];
        out[(size_t)(b * NN + rowbase + i) * DOUT + o] = h;
    }
}

// Per-channel batch stats over (B*N, 64); deterministic tree reduction.
__global__ void bn_stats(const float* __restrict__ h, float* __restrict__ stats) {
    const int c = blockIdx.x;
    const int t = threadIdx.x;
    float s = 0.f, s2 = 0.f;
    for (int r = t; r < NB * NN; r += 256) {
        float v = h[(size_t)r * DOUT + c];
        s += v; s2 += v * v;
    }
    __shared__ float rs[256], rs2[256];
    rs[t] = s; rs2[t] = s2;
    __syncthreads();
    for (int k = 128; k > 0; k >>= 1) {
        if (t < k) { rs[t] += rs[t + k]; rs2[t] += rs2[t + k]; }
        __syncthreads();
    }
    if (t == 0) {
        const float inv_n = 1.0f / (float)(NB * NN);
        float mean = rs[0] * inv_n;
        float var = rs2[0] * inv_n - mean * mean;   // biased, as torch BN
        stats[c] = mean;
        stats[DOUT + c] = rsqrtf(var + 1e-5f);
    }
}

__global__ void bn_selu(float* __restrict__ out, const float* __restrict__ stats,
                        const float* __restrict__ gamma, const float* __restrict__ beta) {
    const int idx = blockIdx.x * 256 + threadIdx.x;
    const int c = idx & 63;
    float v = out[idx];
    float y = (v - stats[c]) * stats[DOUT + c] * gamma[c] + beta[c];
    const float scale = 1.0507009873554805f;
    const float alpha = 1.6732632423543772f;
    out[idx] = y > 0.0f ? scale * y : scale * alpha * (__expf(y) - 1.0f);
}

extern "C" void kernel_launch(void* const* d_in, const int* in_sizes, int n_in,
                              void* d_out, int out_size, void* d_ws, size_t ws_size,
                              hipStream_t stream) {
    const float* x    = (const float*)d_in[0];
    const float* apw  = (const float*)d_in[1];
    const float* apb  = (const float*)d_in[2];
    const float* attw = (const float*)d_in[3];
    const float* pww  = (const float*)d_in[4];
    const float* pwb  = (const float*)d_in[5];
    const float* pow_ = (const float*)d_in[6];
    const float* pob  = (const float*)d_in[7];
    const float* gmm  = (const float*)d_in[8];
    const float* bta  = (const float*)d_in[9];
    float* out = (float*)d_out;
    float* stats = (float*)d_ws;                                 // 128 floats
    unsigned short* xbf = (unsigned short*)((char*)d_ws + 1024); // 512 KB bf16 x

    x_to_bf16<<<256, 256, 0, stream>>>(x, xbf);
    gat_main<<<NB * NN / TI, 512, 0, stream>>>(x, xbf, apw, apb, attw, pww, pwb, pow_, pob, out);
    bn_stats<<<DOUT, 256, 0, stream>>>(out, stats);
    bn_selu<<<(NB * NN * DOUT) / 256, 256, 0, stream>>>(out, stats, gmm, bta);
}

// Round 8
// 93.804 us; speedup vs baseline: 1.9695x; 1.0079x over previous
//
#include <hip/hip_runtime.h>
#include <math.h>

#define NB 4
#define NN 512
#define DIN 128
#define DOUT 64
#define TI 2
#define CHROWS 32
#define NCH (NN / CHROWS)

typedef __attribute__((ext_vector_type(8))) short short8;
typedef __attribute__((ext_vector_type(8))) unsigned short ushort8;
typedef __attribute__((ext_vector_type(4))) float f32x4;

__device__ __forceinline__ unsigned short f2bf(float f) {
    union { float f; unsigned u; } v; v.f = f;
    unsigned r = v.u + 0x7fffu + ((v.u >> 16) & 1u);  // round-nearest-even
    return (unsigned short)(r >> 16);
}

__device__ __forceinline__ float bf2f(unsigned short u) {
    union { unsigned u; float f; } v; v.u = ((unsigned)u) << 16; return v.f;
}

// Convert x (B*N*DIN f32) to bf16 in workspace.
__global__ void x_to_bf16(const float* __restrict__ x, unsigned short* __restrict__ xbf) {
    const int idx = blockIdx.x * 256 + threadIdx.x;   // 0..65535
    float4 v = ((const float4*)x)[idx];
    ushort4 o;
    o.x = f2bf(v.x); o.y = f2bf(v.y); o.z = f2bf(v.z); o.w = f2bf(v.w);
    ((ushort4*)xbf)[idx] = o;
}

__global__ __launch_bounds__(512, 4) void gat_main(
    const float* __restrict__ x,            // [B][N][128] f32
    const unsigned short* __restrict__ xbf, // [B][N][128] bf16
    const float* __restrict__ apw,   // [64][128]
    const float* __restrict__ apb,   // [64]
    const float* __restrict__ attw,  // [64]
    const float* __restrict__ pww,   // [64][128]
    const float* __restrict__ pwb,   // [64]
    const float* __restrict__ pow_,  // [64][128]
    const float* __restrict__ pob,   // [64]
    float* __restrict__ out)         // [B*N][64] pre-BN h
{
    __shared__ unsigned short xt[2][CHROWS * DIN];  // 2 x 8 KB double-buffered tile
    __shared__ float scp[4][TI][NN];                // 16 KB partial scores / exp
    __shared__ float xis[TI][DIN];                  // 1 KB query rows f32
    __shared__ float aw_s[DOUT];
    __shared__ float ab_s[DOUT];
    __shared__ float red_s[8][TI];
    __shared__ float bcs[TI];

    // epilogue scratch aliased into xt (xt dead after score loop; 7 KB < 16 KB)
    float* pagg = (float*)&xt[0][0];              // [4][TI][DIN] 4 KB
    float* aggs = pagg + 4 * TI * DIN;            // [TI][DIN] 1 KB
    float* pr   = aggs + TI * DIN;                // [8][DOUT] 2 KB

    const int t = threadIdx.x;
    const int blk = blockIdx.x;              // 0..1023
    const int b = blk >> 8;                  // 256 blocks per batch
    const int rowbase = (blk & 255) * TI;
    const float* xb = x + (size_t)b * NN * DIN;
    const unsigned short* xbb = xbf + (size_t)b * NN * DIN;

    if (t < TI * DIN) {
        int i = t >> 7, d = t & 127;
        xis[i][d] = xb[(size_t)(rowbase + i) * DIN + d];
    }
    if (t < 64) { aw_s[t] = attw[t]; ab_s[t] = apb[t]; }
    __syncthreads();

    const int lane = t & 63, wid = t >> 6;
    const int og = wid & 3;          // o in [og*16, og*16+16)
    const int jsub = wid >> 2;       // j-rows [jsub*16, jsub*16+16) of each chunk
    const int lr = lane & 15;
    const int g = lane >> 4;
    const int g8 = g * 8;

    // staging offsets (bytes), fixed per thread: one ushort8 (16 B) per thread per chunk
    const int st_row = t >> 4, st_gr = t & 15;
    const int st_off = st_row * 256 + ((st_gr ^ (st_row & 7)) << 4);
    // read offsets, fixed per thread
    const int rloc = jsub * 16 + lr;
    int rdoff[4];
    #pragma unroll
    for (int ks = 0; ks < 4; ++ks)
        rdoff[ks] = rloc * 256 + ((((ks * 4 + g) ^ (lr & 7))) << 4);

    // prologue: issue chunk-0 load, do A-prep under it, then write + barrier
    ushort8 v0 = ((const ushort8*)xbb)[t];

    // A-fragments: afr[i][ks], row o = og*16+lr, k = ks*32+g8+[0..8)
    short8 afr[TI][4];
    {
        const float* wrow = apw + (size_t)(og * 16 + lr) * DIN;
        #pragma unroll
        for (int ks = 0; ks < 4; ++ks) {
            float4 w0 = *(const float4*)(wrow + ks * 32 + g8);
            float4 w1 = *(const float4*)(wrow + ks * 32 + g8 + 4);
            #pragma unroll
            for (int i = 0; i < TI; ++i) {
                const float* xk = &xis[i][ks * 32 + g8];
                short8 fr;
                fr[0] = (short)f2bf(w0.x * xk[0]);
                fr[1] = (short)f2bf(w0.y * xk[1]);
                fr[2] = (short)f2bf(w0.z * xk[2]);
                fr[3] = (short)f2bf(w0.w * xk[3]);
                fr[4] = (short)f2bf(w1.x * xk[4]);
                fr[5] = (short)f2bf(w1.y * xk[5]);
                fr[6] = (short)f2bf(w1.z * xk[6]);
                fr[7] = (short)f2bf(w1.w * xk[7]);
                afr[i][ks] = fr;
            }
        }
    }

    // per-lane tanh constants for its 4 o's: o = og*16 + g*4 + r
    // w*tanh(T) = w - 2w * rcp(exp2(T*C2) + 1),  C2 = 2*log2(e)
    const float C2 = 2.885390081777927f;
    float awm2[4], abc[4], sumw = 0.0f;
    #pragma unroll
    for (int r = 0; r < 4; ++r) {
        const int o = og * 16 + g * 4 + r;
        float w = aw_s[o];
        awm2[r] = -2.0f * w;
        abc[r] = ab_s[o] * C2;
        sumw += w;
    }

    *(ushort8*)((char*)&xt[0][0] + st_off) = v0;
    __syncthreads();   // xt[0] visible

    int p = 0;
    #pragma unroll 2
    for (int ch = 0; ch < NCH; ++ch) {
        ushort8 vnext;
        if (ch + 1 < NCH) vnext = ((const ushort8*)xbb)[(ch + 1) * (CHROWS * DIN / 8) + t];

        // compute current chunk from xt[p]
        const int j0 = ch * CHROWS + jsub * 16;
        short8 bfr[4];
        #pragma unroll
        for (int ks = 0; ks < 4; ++ks)
            bfr[ks] = *(const short8*)((const char*)&xt[p][0] + rdoff[ks]);

        #pragma unroll
        for (int i = 0; i < TI; ++i) {
            f32x4 acc = {0.f, 0.f, 0.f, 0.f};
            #pragma unroll
            for (int ks = 0; ks < 4; ++ks)
                acc = __builtin_amdgcn_mfma_f32_16x16x32_bf16(afr[i][ks], bfr[ks], acc, 0, 0, 0);
            float sp = sumw;
            #pragma unroll
            for (int r = 0; r < 4; ++r) {
                float arg = fmaf(acc[r], C2, abc[r]);
                float u, rc;
                asm("v_exp_f32 %0, %1" : "=v"(u) : "v"(arg));
                float den = u + 1.0f;
                asm("v_rcp_f32 %0, %1" : "=v"(rc) : "v"(den));
                sp = fmaf(awm2[r], rc, sp);
            }
            sp += __shfl_xor(sp, 16);
            sp += __shfl_xor(sp, 32);
            if (lane < 16) scp[og][i][j0 + lane] = sp;
        }

        // write next chunk into the other buffer, then one barrier
        if (ch + 1 < NCH)
            *(ushort8*)((char*)&xt[p ^ 1][0] + st_off) = vnext;
        __syncthreads();
        p ^= 1;
    }

    // softmax over j (no max-subtraction: |score| <= sum|w| ~ 8, f32-safe)
    float s0 = scp[0][0][t] + scp[1][0][t] + scp[2][0][t] + scp[3][0][t];
    float s1 = scp[0][1][t] + scp[1][1][t] + scp[2][1][t] + scp[3][1][t];
    float e0 = __expf(s0), e1 = __expf(s1);
    float ss0 = e0, ss1 = e1;
    #pragma unroll
    for (int msk = 1; msk < 64; msk <<= 1) {
        ss0 += __shfl_xor(ss0, msk);
        ss1 += __shfl_xor(ss1, msk);
    }
    if (lane == 0) { red_s[wid][0] = ss0; red_s[wid][1] = ss1; }
    __syncthreads();   // also guards scp re-write below
    scp[0][0][t] = e0;   // esc[0][j]
    scp[0][1][t] = e1;   // esc[1][j]
    if (t < TI) {
        float sm = 0.f;
        #pragma unroll
        for (int w = 0; w < 8; ++w) sm += red_s[w][t];
        bcs[t] = 1.0f / sm;
    }
    __syncthreads();

    // agg[i][d] = invs_i * sum_j e[i][j] * x[b,j,d]
    const float* esc0 = &scp[0][0][0];
    const float* esc1 = &scp[0][1][0];
    {
        const int d = t & 127, q = t >> 7;
        const unsigned short* xc = xbb + d;
        float a0 = 0.f, a1 = 0.f;
        for (int jj = q * 128; jj < q * 128 + 128; ++jj) {
            float xv = bf2f(xc[(size_t)jj * DIN]);
            a0 = fmaf(esc0[jj], xv, a0);
            a1 = fmaf(esc1[jj], xv, a1);
        }
        pagg[(q * TI + 0) * DIN + d] = a0;
        pagg[(q * TI + 1) * DIN + d] = a1;
    }
    __syncthreads();
    if (t < TI * DIN) {
        const int i = t >> 7, d = t & 127;
        aggs[i * DIN + d] = (pagg[(0 * TI + i) * DIN + d] + pagg[(1 * TI + i) * DIN + d] +
                             pagg[(2 * TI + i) * DIN + d] + pagg[(3 * TI + i) * DIN + d]) * bcs[i];
    }
    __syncthreads();

    // projections: pi = t>>6 in 0..7 -> i = pi>>2, d-part = pi&3 (32 d each)
    {
        const int o = t & 63, pi = t >> 6;
        const int i = pi >> 2, part = pi & 3;
        const float* w1 = pww + (size_t)o * DIN + part * 32;
        const float* w2 = pow_ + (size_t)o * DIN + part * 32;
        const float* ag = aggs + i * DIN + part * 32;
        const float* xr = &xis[i][part * 32];
        float sum = 0.0f;
        #pragma unroll
        for (int dd = 0; dd < 32; ++dd)
            sum += w1[dd] * ag[dd] + w2[dd] * xr[dd];
        pr[pi * DOUT + o] = sum;
    }
    __syncthreads();
    if (t < TI * DOUT) {
        const int i = t >> 6, o = t & 63;
        float h = pr[(i * 4 + 0) * DOUT + o] + pr[(i * 4 + 1) * DOUT + o] +
                  pr[(i * 4 + 2) * DOUT + o] + pr[(i * 4 + 3) * DOUT + o] +
                  pwb[o] + pob[o];
        out[(size_t)(b * NN + rowbase + i) * DOUT + o] = h;
    }
}

// Per-channel batch stats over (B*N, 64); deterministic tree reduction.
__global__ void bn_stats(const float* __restrict__ h, float* __restrict__ stats) {
    const int c = blockIdx.x;
    const int t = threadIdx.x;
    float s = 0.f, s2 = 0.f;
    for (int r = t; r < NB * NN; r += 256) {
        float v = h[(size_t)r * DOUT + c];
        s += v; s2 += v * v;
    }
    __shared__ float rs[256], rs2[256];
    rs[t] = s; rs2[t] = s2;
    __syncthreads();
    for (int k = 128; k > 0; k >>= 1) {
        if (t < k) { rs[t] += rs[t + k]; rs2[t] += rs2[t + k]; }
        __syncthreads();
    }
    if (t == 0) {
        const float inv_n = 1.0f / (float)(NB * NN);
        float mean = rs[0] * inv_n;
        float var = rs2[0] * inv_n - mean * mean;   // biased, as torch BN
        stats[c] = mean;
        stats[DOUT + c] = rsqrtf(var + 1e-5f);
    }
}

__global__ void bn_selu(float* __restrict__ out, const float* __restrict__ stats,
                        const float* __restrict__ gamma, const float* __restrict__ beta) {
    const int idx = blockIdx.x * 256 + threadIdx.x;
    const int c = idx & 63;
    float v = out[idx];
    float y = (v - stats[c]) * stats[DOUT + c] * gamma[c] + beta[c];
    const float scale = 1.0507009873554805f;
    const float alpha = 1.6732632423543772f;
    out[idx] = y > 0.0f ? scale * y : scale * alpha * (__expf(y) - 1.0f);
}

extern "C" void kernel_launch(void* const* d_in, const int* in_sizes, int n_in,
                              void* d_out, int out_size, void* d_ws, size_t ws_size,
                              hipStream_t stream) {
    const float* x    = (const float*)d_in[0];
    const float* apw  = (const float*)d_in[1];
    const float* apb  = (const float*)d_in[2];
    const float* attw = (const float*)d_in[3];
    const float* pww  = (const float*)d_in[4];
    const float* pwb  = (const float*)d_in[5];
    const float* pow_ = (const float*)d_in[6];
    const float* pob  = (const float*)d_in[7];
    const float* gmm  = (const float*)d_in[8];
    const float* bta  = (const float*)d_in[9];
    float* out = (float*)d_out;
    float* stats = (float*)d_ws;                                 // 128 floats
    unsigned short* xbf = (unsigned short*)((char*)d_ws + 1024); // 512 KB bf16 x

    x_to_bf16<<<256, 256, 0, stream>>>(x, xbf);
    gat_main<<<NB * NN / TI, 512, 0, stream>>>(x, xbf, apw, apb, attw, pww, pwb, pow_, pob, out);
    bn_stats<<<DOUT, 256, 0, stream>>>(out, stats);
    bn_selu<<<(NB * NN * DOUT) / 256, 256, 0, stream>>>(out, stats, gmm, bta);
}

// Round 9
// 71.951 us; speedup vs baseline: 2.5676x; 1.3037x over previous
//
#include <hip/hip_runtime.h>
#include <math.h>

#define NB 4
#define NN 512
#define DIN 128
#define DOUT 64
#define TI 2
#define CHROWS 32
#define NCH (NN / CHROWS)

typedef __attribute__((ext_vector_type(8))) short short8;
typedef __attribute__((ext_vector_type(8))) unsigned short ushort8;
typedef __attribute__((ext_vector_type(4))) float f32x4;

__device__ __forceinline__ unsigned short f2bf(float f) {
    union { float f; unsigned u; } v; v.f = f;
    unsigned r = v.u + 0x7fffu + ((v.u >> 16) & 1u);  // round-nearest-even
    return (unsigned short)(r >> 16);
}

__device__ __forceinline__ float bf2f(unsigned short u) {
    union { unsigned u; float f; } v; v.u = ((unsigned)u) << 16; return v.f;
}

// Convert x (B*N*DIN f32) to bf16 in workspace.
__global__ void x_to_bf16(const float* __restrict__ x, unsigned short* __restrict__ xbf) {
    const int idx = blockIdx.x * 256 + threadIdx.x;   // 0..65535
    float4 v = ((const float4*)x)[idx];
    ushort4 o;
    o.x = f2bf(v.x); o.y = f2bf(v.y); o.z = f2bf(v.z); o.w = f2bf(v.w);
    ((ushort4*)xbf)[idx] = o;
}

__global__ __launch_bounds__(512, 4) void gat_main(
    const float* __restrict__ x,            // [B][N][128] f32
    const unsigned short* __restrict__ xbf, // [B][N][128] bf16
    const float* __restrict__ apw,   // [64][128]
    const float* __restrict__ apb,   // [64]
    const float* __restrict__ attw,  // [64]
    const float* __restrict__ pww,   // [64][128]
    const float* __restrict__ pwb,   // [64]
    const float* __restrict__ pow_,  // [64][128]
    const float* __restrict__ pob,   // [64]
    float* __restrict__ out)         // [B*N][64] pre-BN h
{
    __shared__ unsigned short xt[2][CHROWS * DIN];  // 2 x 8 KB double-buffered tile
    __shared__ float scp[4][TI][NN];                // 16 KB partial scores / exp
    __shared__ float xis[TI][DIN];                  // 1 KB query rows f32
    __shared__ float aw_s[DOUT];
    __shared__ float ab_s[DOUT];
    __shared__ float red_s[8][TI];
    __shared__ float bcs[TI];

    // epilogue scratch aliased into xt (xt dead after score loop; 11.2 KB < 16 KB)
    float* pagg = (float*)&xt[0][0];              // [8][TI][DIN] 8 KB
    float* aggs = pagg + 8 * TI * DIN;            // [TI][DIN] 1 KB
    float* pr   = aggs + TI * DIN;                // [8][DOUT] 2 KB

    const int t = threadIdx.x;
    const int blk = blockIdx.x;              // 0..1023
    const int b = blk >> 8;                  // 256 blocks per batch
    const int rowbase = (blk & 255) * TI;
    const float* xb = x + (size_t)b * NN * DIN;
    const unsigned short* xbb = xbf + (size_t)b * NN * DIN;

    if (t < TI * DIN) {
        int i = t >> 7, d = t & 127;
        xis[i][d] = xb[(size_t)(rowbase + i) * DIN + d];
    }
    if (t < 64) { aw_s[t] = attw[t]; ab_s[t] = apb[t]; }
    __syncthreads();

    const int lane = t & 63, wid = t >> 6;
    const int og = wid & 3;          // o in [og*16, og*16+16)
    const int jsub = wid >> 2;       // j-rows [jsub*16, jsub*16+16) of each chunk
    const int lr = lane & 15;
    const int g = lane >> 4;
    const int g8 = g * 8;

    // staging offsets (bytes), fixed per thread: one ushort8 (16 B) per thread per chunk
    const int st_row = t >> 4, st_gr = t & 15;
    const int st_off = st_row * 256 + ((st_gr ^ (st_row & 7)) << 4);
    // read offsets, fixed per thread
    const int rloc = jsub * 16 + lr;
    int rdoff[4];
    #pragma unroll
    for (int ks = 0; ks < 4; ++ks)
        rdoff[ks] = rloc * 256 + ((((ks * 4 + g) ^ (lr & 7))) << 4);

    // prologue: issue chunk-0 load, do A-prep under it, then write + barrier
    ushort8 v0 = ((const ushort8*)xbb)[t];

    // A-fragments: afr[i][ks], row o = og*16+lr, k = ks*32+g8+[0..8)
    short8 afr[TI][4];
    {
        const float* wrow = apw + (size_t)(og * 16 + lr) * DIN;
        #pragma unroll
        for (int ks = 0; ks < 4; ++ks) {
            float4 w0 = *(const float4*)(wrow + ks * 32 + g8);
            float4 w1 = *(const float4*)(wrow + ks * 32 + g8 + 4);
            #pragma unroll
            for (int i = 0; i < TI; ++i) {
                const float* xk = &xis[i][ks * 32 + g8];
                short8 fr;
                fr[0] = (short)f2bf(w0.x * xk[0]);
                fr[1] = (short)f2bf(w0.y * xk[1]);
                fr[2] = (short)f2bf(w0.z * xk[2]);
                fr[3] = (short)f2bf(w0.w * xk[3]);
                fr[4] = (short)f2bf(w1.x * xk[4]);
                fr[5] = (short)f2bf(w1.y * xk[5]);
                fr[6] = (short)f2bf(w1.z * xk[6]);
                fr[7] = (short)f2bf(w1.w * xk[7]);
                afr[i][ks] = fr;
            }
        }
    }

    // per-lane tanh constants for its 4 o's: o = og*16 + g*4 + r
    // w*tanh(T) = w - 2w * rcp(exp2(T*C2) + 1),  C2 = 2*log2(e)
    const float C2 = 2.885390081777927f;
    float awm2[4], abc[4], sumw = 0.0f;
    #pragma unroll
    for (int r = 0; r < 4; ++r) {
        const int o = og * 16 + g * 4 + r;
        float w = aw_s[o];
        awm2[r] = -2.0f * w;
        abc[r] = ab_s[o] * C2;
        sumw += w;
    }

    *(ushort8*)((char*)&xt[0][0] + st_off) = v0;
    __syncthreads();   // xt[0] visible

    // T15 pipeline: MFMA(ch) overlaps post-processing of accP = acc(ch-1)
    int p = 0;
    f32x4 accP[TI];
    #pragma unroll 2
    for (int ch = 0; ch < NCH; ++ch) {
        ushort8 vnext;
        if (ch + 1 < NCH) vnext = ((const ushort8*)xbb)[(ch + 1) * (CHROWS * DIN / 8) + t];

        short8 bfr[4];
        #pragma unroll
        for (int ks = 0; ks < 4; ++ks)
            bfr[ks] = *(const short8*)((const char*)&xt[p][0] + rdoff[ks]);

        f32x4 accC[TI];
        #pragma unroll
        for (int i = 0; i < TI; ++i) {
            f32x4 acc = {0.f, 0.f, 0.f, 0.f};
            #pragma unroll
            for (int ks = 0; ks < 4; ++ks)
                acc = __builtin_amdgcn_mfma_f32_16x16x32_bf16(afr[i][ks], bfr[ks], acc, 0, 0, 0);
            accC[i] = acc;
        }

        // post-process PREVIOUS chunk while MFMA pipe drains
        if (ch > 0) {
            const int jp = (ch - 1) * CHROWS + jsub * 16;
            float sp[TI];
            #pragma unroll
            for (int i = 0; i < TI; ++i) {
                float s = sumw;
                #pragma unroll
                for (int r = 0; r < 4; ++r) {
                    float arg = fmaf(accP[i][r], C2, abc[r]);
                    float u, rc;
                    asm("v_exp_f32 %0, %1" : "=v"(u) : "v"(arg));
                    float den = u + 1.0f;
                    asm("v_rcp_f32 %0, %1" : "=v"(rc) : "v"(den));
                    s = fmaf(awm2[r], rc, s);
                }
                sp[i] = s;
            }
            #pragma unroll
            for (int i = 0; i < TI; ++i) sp[i] += __shfl_xor(sp[i], 16);
            #pragma unroll
            for (int i = 0; i < TI; ++i) sp[i] += __shfl_xor(sp[i], 32);
            if (lane < 16) {
                #pragma unroll
                for (int i = 0; i < TI; ++i) scp[og][i][jp + lane] = sp[i];
            }
        }

        if (ch + 1 < NCH)
            *(ushort8*)((char*)&xt[p ^ 1][0] + st_off) = vnext;
        __syncthreads();
        #pragma unroll
        for (int i = 0; i < TI; ++i) accP[i] = accC[i];
        p ^= 1;
    }
    // final post for chunk NCH-1
    {
        const int jp = (NCH - 1) * CHROWS + jsub * 16;
        float sp[TI];
        #pragma unroll
        for (int i = 0; i < TI; ++i) {
            float s = sumw;
            #pragma unroll
            for (int r = 0; r < 4; ++r) {
                float arg = fmaf(accP[i][r], C2, abc[r]);
                float u, rc;
                asm("v_exp_f32 %0, %1" : "=v"(u) : "v"(arg));
                float den = u + 1.0f;
                asm("v_rcp_f32 %0, %1" : "=v"(rc) : "v"(den));
                s = fmaf(awm2[r], rc, s);
            }
            sp[i] = s;
        }
        #pragma unroll
        for (int i = 0; i < TI; ++i) sp[i] += __shfl_xor(sp[i], 16);
        #pragma unroll
        for (int i = 0; i < TI; ++i) sp[i] += __shfl_xor(sp[i], 32);
        if (lane < 16) {
            #pragma unroll
            for (int i = 0; i < TI; ++i) scp[og][i][jp + lane] = sp[i];
        }
    }
    __syncthreads();

    // softmax over j (no max-subtraction: |score| <= sum|w| ~ 8, f32-safe)
    float s0 = scp[0][0][t] + scp[1][0][t] + scp[2][0][t] + scp[3][0][t];
    float s1 = scp[0][1][t] + scp[1][1][t] + scp[2][1][t] + scp[3][1][t];
    float e0 = __expf(s0), e1 = __expf(s1);
    float ss0 = e0, ss1 = e1;
    #pragma unroll
    for (int msk = 1; msk < 64; msk <<= 1) {
        ss0 += __shfl_xor(ss0, msk);
        ss1 += __shfl_xor(ss1, msk);
    }
    if (lane == 0) { red_s[wid][0] = ss0; red_s[wid][1] = ss1; }
    __syncthreads();   // also guards scp re-write below
    scp[0][0][t] = e0;   // esc[0][j]
    scp[0][1][t] = e1;   // esc[1][j]
    if (t < TI) {
        float sm = 0.f;
        #pragma unroll
        for (int w = 0; w < 8; ++w) sm += red_s[w][t];
        bcs[t] = 1.0f / sm;
    }
    __syncthreads();

    // agg[i][d] = invs_i * sum_j e[i][j] * x[b,j,d]  — ushort2-vectorized
    const float* esc0 = &scp[0][0][0];
    const float* esc1 = &scp[0][1][0];
    {
        const int d0 = (t & 63) * 2, q = t >> 6;   // q in 0..7, 64 jj each
        const unsigned short* xc = xbb + d0;
        float a00 = 0.f, a01 = 0.f, a10 = 0.f, a11 = 0.f;
        #pragma unroll 4
        for (int jj = q * 64; jj < q * 64 + 64; ++jj) {
            ushort2 xv = *(const ushort2*)(xc + (size_t)jj * DIN);
            float x0 = bf2f(xv.x), x1 = bf2f(xv.y);
            float e0v = esc0[jj], e1v = esc1[jj];
            a00 = fmaf(e0v, x0, a00); a01 = fmaf(e0v, x1, a01);
            a10 = fmaf(e1v, x0, a10); a11 = fmaf(e1v, x1, a11);
        }
        pagg[(q * TI + 0) * DIN + d0] = a00;
        pagg[(q * TI + 0) * DIN + d0 + 1] = a01;
        pagg[(q * TI + 1) * DIN + d0] = a10;
        pagg[(q * TI + 1) * DIN + d0 + 1] = a11;
    }
    __syncthreads();
    if (t < TI * DIN) {
        const int i = t >> 7, d = t & 127;
        float s = 0.f;
        #pragma unroll
        for (int q = 0; q < 8; ++q) s += pagg[(q * TI + i) * DIN + d];
        aggs[i * DIN + d] = s * bcs[i];
    }
    __syncthreads();

    // projections: pi = t>>6 in 0..7 -> i = pi>>2, d-part = pi&3 (32 d each)
    {
        const int o = t & 63, pi = t >> 6;
        const int i = pi >> 2, part = pi & 3;
        const float* w1 = pww + (size_t)o * DIN + part * 32;
        const float* w2 = pow_ + (size_t)o * DIN + part * 32;
        const float* ag = aggs + i * DIN + part * 32;
        const float* xr = &xis[i][part * 32];
        float sum = 0.0f;
        #pragma unroll
        for (int dd = 0; dd < 32; ++dd)
            sum += w1[dd] * ag[dd] + w2[dd] * xr[dd];
        pr[pi * DOUT + o] = sum;
    }
    __syncthreads();
    if (t < TI * DOUT) {
        const int i = t >> 6, o = t & 63;
        float h = pr[(i * 4 + 0) * DOUT + o] + pr[(i * 4 + 1) * DOUT + o] +
                  pr[(i * 4 + 2) * DOUT + o] + pr[(i * 4 + 3) * DOUT + o] +
                  pwb[o] + pob[o];
        out[(size_t)(b * NN + rowbase + i) * DOUT + o] = h;
    }
}

// Per-channel batch stats over (B*N, 64); deterministic tree reduction.
__global__ void bn_stats(const float* __restrict__ h, float* __restrict__ stats) {
    const int c = blockIdx.x;
    const int t = threadIdx.x;
    float s = 0.f, s2 = 0.f;
    for (int r = t; r < NB * NN; r += 256) {
        float v = h[(size_t)r * DOUT + c];
        s += v; s2 += v * v;
    }
    __shared__ float rs[256], rs2[256];
    rs[t] = s; rs2[t] = s2;
    __syncthreads();
    for (int k = 128; k > 0; k >>= 1) {
        if (t < k) { rs[t] += rs[t + k]; rs2[t] += rs2[t + k]; }
        __syncthreads();
    }
    if (t == 0) {
        const float inv_n = 1.0f / (float)(NB * NN);
        float mean = rs[0] * inv_n;
        float var = rs2[0] * inv_n - mean * mean;   // biased, as torch BN
        stats[c] = mean;
        stats[DOUT + c] = rsqrtf(var + 1e-5f);
    }
}

__global__ void bn_selu(float* __restrict__ out, const float* __restrict__ stats,
                        const float* __restrict__ gamma, const float* __restrict__ beta) {
    const int idx = blockIdx.x * 256 + threadIdx.x;
    const int c = idx & 63;
    float v = out[idx];
    float y = (v - stats[c]) * stats[DOUT + c] * gamma[c] + beta[c];
    const float scale = 1.0507009873554805f;
    const float alpha = 1.6732632423543772f;
    out[idx] = y > 0.0f ? scale * y : scale * alpha * (__expf(y) - 1.0f);
}

extern "C" void kernel_launch(void* const* d_in, const int* in_sizes, int n_in,
                              void* d_out, int out_size, void* d_ws, size_t ws_size,
                              hipStream_t stream) {
    const float* x    = (const float*)d_in[0];
    const float* apw  = (const float*)d_in[1];
    const float* apb  = (const float*)d_in[2];
    const float* attw = (const float*)d_in[3];
    const float* pww  = (const float*)d_in[4];
    const float* pwb  = (const float*)d_in[5];
    const float* pow_ = (const float*)d_in[6];
    const float* pob  = (const float*)d_in[7];
    const float* gmm  = (const float*)d_in[8];
    const float* bta  = (const float*)d_in[9];
    float* out = (float*)d_out;
    float* stats = (float*)d_ws;                                 // 128 floats
    unsigned short* xbf = (unsigned short*)((char*)d_ws + 1024); // 512 KB bf16 x

    x_to_bf16<<<256, 256, 0, stream>>>(x, xbf);
    gat_main<<<NB * NN / TI, 512, 0, stream>>>(x, xbf, apw, apb, attw, pww, pwb, pow_, pob, out);
    bn_stats<<<DOUT, 256, 0, stream>>>(out, stats);
    bn_selu<<<(NB * NN * DOUT) / 256, 256, 0, stream>>>(out, stats, gmm, bta);
}